// Round 2
// 246.144 us; speedup vs baseline: 1.0765x; 1.0765x over previous
//
#include <hip/hip_runtime.h>
#include <hip/hip_bf16.h>

#define B_ 8
#define L_ 512
#define N_ 2048
#define C_ 1024
#define D_ 128

typedef __attribute__((ext_vector_type(8))) short    short8;   // 8 x bf16 bits
typedef __attribute__((ext_vector_type(4))) short    short4v;  // 4 x bf16 bits (8B)
typedef __attribute__((ext_vector_type(8))) _Float16 half8;
typedef __attribute__((ext_vector_type(4))) float    floatx4;

static __device__ __forceinline__ float s2f(short s) {
    return __uint_as_float(((unsigned)(unsigned short)s) << 16);
}
static __device__ __forceinline__ short f2bf(float f) {
    union { __hip_bfloat16 h; short s; } u;
    u.h = __float2bfloat16(f);
    return u.s;
}

struct F8 { float v[8]; };

static __device__ __forceinline__ F8 load8(const void* raw, long off, int is_bf16) {
    F8 r;
    if (is_bf16) {
        short8 x = *reinterpret_cast<const short8*>((const short*)raw + off);
        #pragma unroll
        for (int i = 0; i < 8; ++i) r.v[i] = s2f(x[i]);
    } else {
        const float* p = (const float*)raw + off;
        float4 a = *reinterpret_cast<const float4*>(p);
        float4 b = *reinterpret_cast<const float4*>(p + 4);
        r.v[0]=a.x; r.v[1]=a.y; r.v[2]=a.z; r.v[3]=a.w;
        r.v[4]=b.x; r.v[5]=b.y; r.v[6]=b.z; r.v[7]=b.w;
    }
    return r;
}

static __device__ __forceinline__ float bias_at(const void* raw, int d, int is_bf16) {
    return is_bf16 ? s2f(((const short*)raw)[d]) : ((const float*)raw)[d];
}

static __device__ __forceinline__ void load_lds16(const void* g, void* l) {
    __builtin_amdgcn_global_load_lds(
        (const __attribute__((address_space(1))) void*)g,
        (__attribute__((address_space(3))) void*)l, 16, 0, 0);
}

// ---------------------------------------------------------------------------
// Dtype detection (fp32 vs bf16 world).
// ---------------------------------------------------------------------------
__global__ void detect_kernel(const unsigned* __restrict__ words, int* __restrict__ flag) {
    int cnt = 0;
    for (int i = threadIdx.x; i < 256; i += 64) {
        float lowv = __uint_as_float(words[i] << 16);
        float a = fabsf(lowv);
        if (a >= 1e-5f && a <= 100.0f) cnt++;
    }
    #pragma unroll
    for (int off = 32; off; off >>= 1) cnt += __shfl_down(cnt, off);
    if (threadIdx.x == 0) flag[0] = (cnt > 128) ? 1 : 0;
}

// ---------------------------------------------------------------------------
// fp32 world only: raw fp32 -> bf16 bits.
// ---------------------------------------------------------------------------
__global__ __launch_bounds__(256) void cvt_kernel(const void* __restrict__ in_raw,
                                                  short* __restrict__ out, long n,
                                                  const int* __restrict__ flag) {
    if (*flag) return;
    long i = ((long)blockIdx.x * 256 + threadIdx.x) * 8;
    if (i >= n) return;
    F8 x = load8(in_raw, i, 0);
    short8 o;
    #pragma unroll
    for (int j = 0; j < 8; ++j) o[j] = f2bf(x.v[j]);
    *reinterpret_cast<short8*>(out + i) = o;
}

// ---------------------------------------------------------------------------
// fp32 world only: raw fp32 -> fp16.
// ---------------------------------------------------------------------------
__global__ __launch_bounds__(256) void cvt_half_kernel(const void* __restrict__ in_raw,
                                                       _Float16* __restrict__ out, long n,
                                                       const int* __restrict__ flag) {
    if (*flag) return;
    long i = ((long)blockIdx.x * 256 + threadIdx.x) * 8;
    if (i >= n) return;
    F8 x = load8(in_raw, i, 0);
    half8 o;
    #pragma unroll
    for (int j = 0; j < 8; ++j) o[j] = (_Float16)x.v[j];
    *reinterpret_cast<half8*>(out + i) = o;
}

// ---------------------------------------------------------------------------
// Kernel 1: Q = F @ Wq^T + bq ; K = F @ Wk^T + bk  (fp16 out) — MERGED.
// ---------------------------------------------------------------------------
__global__ __launch_bounds__(512) void proj_kernel(
    const void* __restrict__ Fraw,
    const void* __restrict__ Wq_raw, const void* __restrict__ Wk_raw,
    const _Float16* __restrict__ Wq_h, const _Float16* __restrict__ Wk_h,
    const void* __restrict__ bq_raw, const void* __restrict__ bk_raw,
    _Float16* __restrict__ Q, _Float16* __restrict__ K,
    const int* __restrict__ flag)
{
    const int is_bf16 = *flag;
    const int tid  = threadIdx.x;
    const int wave = tid >> 6;
    const int lane = tid & 63;
    const int quad = lane >> 4;
    const int l16  = lane & 15;
    const long r0  = (long)blockIdx.x * 64;

    const int m0   = (wave & 1) * 32;    // F rows within tile
    const int col0 = (wave >> 1) * 64;   // W rows within 256 (Q|K)

    __shared__ short Ft[64 * 32];    // 4 KB
    __shared__ short Wt[256 * 32];   // 16 KB

    floatx4 acc[2][4] = {};

    const int srow = lane >> 2;
    const int sg   = (lane & 3) ^ ((srow >> 1) & 3);
    const int skoff = sg * 8;

    if (is_bf16) {
        const short* Fr  = (const short*)Fraw;
        const short* Wqr = (const short*)Wq_raw;
        const short* Wkr = (const short*)Wk_raw;
        for (int kb = 0; kb < 32; ++kb) {
            const int k0 = kb * 32;
            #pragma unroll
            for (int jj = 0; jj < 2; ++jj) {
                const int c = wave * 2 + jj;
                const short* Wr = (c < 8) ? Wqr : Wkr;
                const int wrow = (c & 7) * 16 + srow;
                load_lds16(Wr + (long)wrow * C_ + k0 + skoff,
                           Wt + c * 512 + lane * 8);
            }
            if (wave < 4) {
                load_lds16(Fr + (r0 + wave * 16 + srow) * (long)C_ + k0 + skoff,
                           Ft + wave * 512 + lane * 8);
            }
            __syncthreads();

            short8 af[2], bfr[4];
            #pragma unroll
            for (int t = 0; t < 2; ++t) {
                const int row = m0 + t * 16 + l16;
                const int ph  = quad ^ ((row >> 1) & 3);
                af[t] = *reinterpret_cast<const short8*>(Ft + row * 32 + ph * 8);
            }
            #pragma unroll
            for (int u = 0; u < 4; ++u) {
                const int wrow = col0 + u * 16 + l16;
                const int ph   = quad ^ ((wrow >> 1) & 3);
                bfr[u] = *reinterpret_cast<const short8*>(Wt + wrow * 32 + ph * 8);
            }
            #pragma unroll
            for (int t = 0; t < 2; ++t)
                #pragma unroll
                for (int u = 0; u < 4; ++u)
                    acc[t][u] = __builtin_amdgcn_mfma_f32_16x16x32_bf16(af[t], bfr[u], acc[t][u], 0, 0, 0);
            __syncthreads();
        }
    } else {
        _Float16* Fth = (_Float16*)Ft;
        _Float16* Wth = (_Float16*)Wt;
        for (int kb = 0; kb < 32; ++kb) {
            const int k0 = kb * 32;
            #pragma unroll
            for (int jj = 0; jj < 2; ++jj) {
                const int c = wave * 2 + jj;
                const _Float16* Wh = (c < 8) ? Wq_h : Wk_h;
                const int wrow = (c & 7) * 16 + srow;
                load_lds16(Wh + (long)wrow * C_ + k0 + skoff,
                           Wth + c * 512 + lane * 8);
            }
            if (tid < 256) {
                const int frow = tid >> 2;
                const int fg   = (tid & 3) ^ ((frow >> 1) & 3);
                F8 x = load8(Fraw, (r0 + frow) * (long)C_ + k0 + fg * 8, 0);
                half8 h;
                #pragma unroll
                for (int j = 0; j < 8; ++j) h[j] = (_Float16)x.v[j];
                *reinterpret_cast<half8*>(Fth + tid * 8) = h;
            }
            __syncthreads();

            half8 af[2], bfr[4];
            #pragma unroll
            for (int t = 0; t < 2; ++t) {
                const int row = m0 + t * 16 + l16;
                const int ph  = quad ^ ((row >> 1) & 3);
                af[t] = *reinterpret_cast<const half8*>(Fth + row * 32 + ph * 8);
            }
            #pragma unroll
            for (int u = 0; u < 4; ++u) {
                const int wrow = col0 + u * 16 + l16;
                const int ph   = quad ^ ((wrow >> 1) & 3);
                bfr[u] = *reinterpret_cast<const half8*>(Wth + wrow * 32 + ph * 8);
            }
            #pragma unroll
            for (int t = 0; t < 2; ++t)
                #pragma unroll
                for (int u = 0; u < 4; ++u)
                    acc[t][u] = __builtin_amdgcn_mfma_f32_16x16x32_f16(af[t], bfr[u], acc[t][u], 0, 0, 0);
            __syncthreads();
        }
    }

    const bool isK = (col0 >= 128);
    const void* braw = isK ? bk_raw : bq_raw;
    _Float16* Out    = isK ? K : Q;
    #pragma unroll
    for (int u = 0; u < 4; ++u) {
        const int d = (col0 + u * 16 + l16) & 127;
        const float bv = bias_at(braw, d, is_bf16);
        #pragma unroll
        for (int t = 0; t < 2; ++t)
            #pragma unroll
            for (int r = 0; r < 4; ++r) {
                const long row = r0 + m0 + t * 16 + quad * 4 + r;
                Out[row * D_ + d] = (_Float16)(acc[t][u][r] + bv);
            }
    }
}

// ---------------------------------------------------------------------------
// Kernel 2 (FUSED attn+xm): for one batch b and one 64-wide m-tile, compute
//   out[l, m] = ( sum_n L[l,n] * exp(Q[m]·K[n]) ) / Z[m],   Z[m] = sum_n exp
// entirely in one block. P never touches HBM; Z never leaves the block.
//
// Grid 32 m-tiles x 8 batches = 256 blocks = 1/CU. 512 thr = 8 waves; each
// wave owns 64 l-rows x all 64 m-cols (acc 4x4 frags = 64 VGPR).
// Per 128-wide n-chunk:
//   - wave w computes E^T slice (its 16 n-rows x 64 m) = mfma(K-frag, Q-frag)
//   - exp in-register, Z partial in-register, pack 4 bf16 -> swizzled LDS
//   - barrier; out-GEMM consumes P as B-fragments + logits direct from L2
// Double-buffered P (2x16KB) => ONE barrier per chunk.
// Batch = flat_block % 8 so each XCD's working set (logits 2MB + K 0.5MB +
// Q 0.5MB for ONE batch) fits its private 4MB L2.
// ---------------------------------------------------------------------------
__global__ __launch_bounds__(512, 2) void fused_attn_xm_kernel(
    const void* __restrict__ Lraw,   // [B,L,N] raw (bf16 world)
    const short* __restrict__ Lcvt,  // [B,L,N] bf16 bits (fp32 world)
    const _Float16* __restrict__ Q,  // [B,N,D] fp16
    const _Float16* __restrict__ K,  // [B,N,D] fp16
    void* __restrict__ OutRaw,
    const int* __restrict__ flag)
{
    const int is_bf16 = *flag;
    const int f    = blockIdx.y * 32 + blockIdx.x;   // flat dispatch index
    const int b    = f & 7;                           // XCD-affinity: batch = f % 8
    const int m0   = (f >> 3) * 64;                   // m-tile base
    const int wave = threadIdx.x >> 6;
    const int lane = threadIdx.x & 63;
    const int quad = lane >> 4;
    const int l16  = lane & 15;

    __shared__ short P0[64 * 128];   // 16 KB
    __shared__ short P1[64 * 128];   // 16 KB
    __shared__ float Zs[64];

    if (threadIdx.x < 64) Zs[threadIdx.x] = 0.0f;

    const short*    Lb = (is_bf16 ? (const short*)Lraw : Lcvt) + (long)b * L_ * N_;
    const _Float16* Qb = Q + (long)b * N_ * D_;
    const _Float16* Kb = K + (long)b * N_ * D_;

    // Q fragments (B-operand of E^T): m = m0 + u*16 + l16, d = s*32 + quad*8
    half8 bq[4][4];
    #pragma unroll
    for (int u = 0; u < 4; ++u)
        #pragma unroll
        for (int s = 0; s < 4; ++s)
            bq[u][s] = *reinterpret_cast<const half8*>(
                Qb + (long)(m0 + u * 16 + l16) * D_ + s * 32 + quad * 8);

    const int lw  = wave * 64;        // this wave's l-rows
    const int swz = l16 * 2;          // even XOR keeps 16B reads contiguous

    floatx4 acc[4][4] = {};           // [t: l-frag][u: m-frag]
    float zpart[4] = {};

    #pragma unroll 2
    for (int ch = 0; ch < 16; ++ch) {
        const int n0 = ch * 128;
        short* Pb = (ch & 1) ? P1 : P0;

        // ---- E^T = K_slice · Q_tile^T : D[row=n][col=m] ----
        const _Float16* krow = Kb + (long)(n0 + wave * 16 + l16) * D_ + quad * 8;
        floatx4 ae[4] = {};
        #pragma unroll
        for (int s = 0; s < 4; ++s) {
            half8 kf = *reinterpret_cast<const half8*>(krow + s * 32);
            #pragma unroll
            for (int u = 0; u < 4; ++u)
                ae[u] = __builtin_amdgcn_mfma_f32_16x16x32_f16(kf, bq[u][s], ae[u], 0, 0, 0);
        }

        // ---- preload logits fragments (independent of P; overlaps exp+barrier)
        short8 al[4][4];
        #pragma unroll
        for (int t = 0; t < 4; ++t)
            #pragma unroll
            for (int ks = 0; ks < 4; ++ks)
                al[t][ks] = *reinterpret_cast<const short8*>(
                    Lb + (long)(lw + t * 16 + l16) * N_ + n0 + ks * 32 + quad * 8);

        // ---- exp, Z partials, pack 4 consecutive-n bf16, swizzled LDS write
        #pragma unroll
        for (int u = 0; u < 4; ++u) {
            short4v pk;
            #pragma unroll
            for (int r = 0; r < 4; ++r) {
                float e = __expf(ae[u][r]);
                zpart[u] += e;
                pk[r] = f2bf(e);
            }
            const int m = u * 16 + l16;
            // logical 8B slot = wave*4 + quad (n_local/4); phys = slot ^ swz
            *reinterpret_cast<short4v*>(
                Pb + m * 128 + (((wave * 4 + quad) ^ swz) << 2)) = pk;
        }
        __syncthreads();   // all waves' P slices visible; dbuf => single barrier

        // ---- out GEMM: acc[t][u] += L[l, n-chunk] · P[m, n-chunk]^T ----
        #pragma unroll
        for (int ks = 0; ks < 4; ++ks) {
            short8 bp[4];
            #pragma unroll
            for (int u = 0; u < 4; ++u) {
                const int m = u * 16 + l16;
                bp[u] = *reinterpret_cast<const short8*>(
                    Pb + m * 128 + ((((ks * 8 + quad * 2) ^ swz)) << 2));
            }
            #pragma unroll
            for (int t = 0; t < 4; ++t)
                #pragma unroll
                for (int u = 0; u < 4; ++u)
                    acc[t][u] = __builtin_amdgcn_mfma_f32_16x16x32_bf16(
                        al[t][ks], bp[u], acc[t][u], 0, 0, 0);
        }
    }

    // ---- Z: reduce quads within wave, then waves via LDS atomics ----
    #pragma unroll
    for (int u = 0; u < 4; ++u) {
        float z = zpart[u];
        z += __shfl_xor(z, 16);
        z += __shfl_xor(z, 32);
        if (lane < 16) atomicAdd(&Zs[u * 16 + lane], z);
    }
    __syncthreads();

    float invz[4];
    #pragma unroll
    for (int u = 0; u < 4; ++u) invz[u] = 1.0f / Zs[u * 16 + l16];

    // ---- epilogue: divide by Z and store ----
    if (is_bf16) {
        short* Ob = (short*)OutRaw + (long)b * L_ * N_;
        #pragma unroll
        for (int t = 0; t < 4; ++t)
            #pragma unroll
            for (int u = 0; u < 4; ++u)
                #pragma unroll
                for (int r = 0; r < 4; ++r) {
                    const long row = lw + t * 16 + quad * 4 + r;
                    const int  col = m0 + u * 16 + l16;
                    Ob[row * N_ + col] = f2bf(acc[t][u][r] * invz[u]);
                }
    } else {
        float* Ob = (float*)OutRaw + (long)b * L_ * N_;
        #pragma unroll
        for (int t = 0; t < 4; ++t)
            #pragma unroll
            for (int u = 0; u < 4; ++u)
                #pragma unroll
                for (int r = 0; r < 4; ++r) {
                    const long row = lw + t * 16 + quad * 4 + r;
                    const int  col = m0 + u * 16 + l16;
                    Ob[row * N_ + col] = acc[t][u][r] * invz[u];
                }
    }
}

// ---------------------------------------------------------------------------
extern "C" void kernel_launch(void* const* d_in, const int* in_sizes, int n_in,
                              void* d_out, int out_size, void* d_ws, size_t ws_size,
                              hipStream_t stream) {
    const void* logits_raw = d_in[0];
    const void* feats_raw  = d_in[1];
    const void* wq_raw     = d_in[2];
    const void* bq_raw     = d_in[3];
    const void* wk_raw     = d_in[4];
    const void* bk_raw     = d_in[5];

    char* ws = (char*)d_ws;
    size_t off = 0;
    int* flag = (int*)(ws + off);           off += 256;
    short* logb = (short*)(ws + off);       off += (size_t)B_ * L_ * N_ * 2;   // 16 MB
    _Float16* Wq_h = (_Float16*)(ws + off); off += (size_t)D_ * C_ * 2;
    _Float16* Wk_h = (_Float16*)(ws + off); off += (size_t)D_ * C_ * 2;
    _Float16* Q = (_Float16*)(ws + off);    off += (size_t)B_ * N_ * D_ * 2;   // 4 MB
    _Float16* K = (_Float16*)(ws + off);    off += (size_t)B_ * N_ * D_ * 2;   // 4 MB

    hipLaunchKernelGGL(detect_kernel, dim3(1), dim3(64), 0, stream,
                       (const unsigned*)feats_raw, flag);
    hipLaunchKernelGGL(cvt_kernel, dim3((B_ * L_ * N_) / (256 * 8)), dim3(256), 0, stream,
                       logits_raw, logb, (long)B_ * L_ * N_, flag);
    hipLaunchKernelGGL(cvt_half_kernel, dim3((D_ * C_) / (256 * 8)), dim3(256), 0, stream,
                       wq_raw, Wq_h, (long)D_ * C_, flag);
    hipLaunchKernelGGL(cvt_half_kernel, dim3((D_ * C_) / (256 * 8)), dim3(256), 0, stream,
                       wk_raw, Wk_h, (long)D_ * C_, flag);
    hipLaunchKernelGGL(proj_kernel, dim3(B_ * N_ / 64), dim3(512), 0, stream,
                       feats_raw, wq_raw, wk_raw, Wq_h, Wk_h, bq_raw, bk_raw, Q, K, flag);
    hipLaunchKernelGGL(fused_attn_xm_kernel, dim3(N_ / 64, B_), dim3(512), 0, stream,
                       logits_raw, logb, Q, K, d_out, flag);
}